// Round 14
// baseline (116.160 us; speedup 1.0000x reference)
//
#include <hip/hip_runtime.h>
#include <math.h>

#define DIM   128
#define KCAP  1024   // dense cap for sub/obj/rel indices (each fits 10 bits)
#define CW    2048   // AB row width: [0,KCAP)=sub coeffs, [KCAP,2*KCAP)=rel coeffs
#define EPG   10     // edges per 8-lane group in k_alpha
#define EPB   (EPG * 32)   // 320 edges per k_alpha block
#define MT2   64     // M-tile rows per k_gemm2 block
#define KCH2  128    // K-chunk
#define NKC2  (CW / KCH2)   // 16
#define NGEMM ((KCAP / MT2) * NKC2)  // 256
#define NTZ   1024   // tail-zero blocks appended to k_pre
#define NB_SORT 128  // blocks in hist/scatter (must match)

typedef _Float16 h2v __attribute__((ext_vector_type(2)));
struct __align__(8)  H2x2 { h2v a, b; };
struct __align__(16) H2x4 { h2v h0, h1, h2, h3; };
__device__ inline H2x2 pack4(float4 v) {
  H2x2 r;
  r.a = h2v{(_Float16)v.x, (_Float16)v.y};
  r.b = h2v{(_Float16)v.z, (_Float16)v.w};
  return r;
}

// ================== fused precompute (multi-region tiled GEMM) ==================
// regions: 0: T[0:1024]=hidden@Wh | 1: T[1024:2048]=rela@Wh | 2: P1h=half(hidden@Ws)
//          3: P2=rela@Wr (f32) AND P2Ch[(rel,c)]=half(P2+C4); block0 also writes C4
//          4: P2 tail f32 | 5: fb_count=0 only | 6: obj histogram | 7: out tail-zero
// NOTE: the old region-5 serial C4 loop (1 block, 256 dependent global loads)
// was the ~40us straggler dominating every k_pre variant. C4 now comes free
// from region 3's c4v registers.
__global__ __launch_bounds__(256) void k_pre(
    const float* __restrict__ hidden, const float* __restrict__ rela,
    const float* __restrict__ kg, const float* __restrict__ Ws,
    const float* __restrict__ Wr, const float* __restrict__ Wh,
    const float* __restrict__ Wkg, const float* __restrict__ Wkg_b,
    const int* __restrict__ edges, int n_edge, int eps,
    _Float16* __restrict__ P1h, float* __restrict__ P2, _Float16* __restrict__ P2Ch,
    float* __restrict__ T, float* __restrict__ C4,
    int* __restrict__ counts, int* __restrict__ fb_count,
    float* __restrict__ out, int n_node,
    int MR, int n_rel, int NR2, int nbA, int nbP2C, int nbD) {
  __shared__ float4 smem[32 * 32];   // 16 KB: input tile OR hist
  __shared__ float4 smemW[32 * 32];  // 16 KB: W chunk (32 k-rows x 128 cols)
  int t = threadIdx.x;
  int rb = blockIdx.x;
  int region;
  if (rb < nbA) region = 0;
  else if ((rb -= nbA) < nbA) region = 1;
  else if ((rb -= nbA) < nbA) region = 2;
  else if ((rb -= nbA) < nbP2C) region = 3;
  else if ((rb -= nbP2C) < nbD) region = 4;
  else if ((rb -= nbD) < 1) region = 5;
  else if ((rb -= 1) < NB_SORT) region = 6;
  else { rb -= NB_SORT; region = 7; }

  if (region == 7) {  // out tail-zero: rows [MR, n_node)
    long long s = (long long)MR * 32;
    long long tot = (long long)n_node * 32;
    long long i = s + (long long)rb * 256 + t;
    long long stride = (long long)NTZ * 256;
    float4 z{0.f, 0.f, 0.f, 0.f};
    float4* o4 = (float4*)out;
    for (; i < tot; i += stride) o4[i] = z;
    return;
  }
  if (region == 5) {  // fb_count zero only (C4 now written by region 3 block 0)
    if (t == 0) *fb_count = 0;
    return;
  }
  if (region == 6) {  // per-block obj histogram -> counts[rb][o] (coalesced)
    int* hist = (int*)smem;
    for (int i = t; i < KCAP; i += 256) hist[i] = 0;
    __syncthreads();
    int s = rb * eps;
    int e = s + eps; if (e > n_edge) e = n_edge;
    for (int i = s + t; i < e; i += 256) {
      int rel = edges[(long long)i * 6 + 2];
      int2 so = *(const int2*)(edges + (long long)i * 6 + 4);
      if (so.x < MR && so.y < MR && rel < NR2) atomicAdd(&hist[so.y], 1);
    }
    __syncthreads();
    for (int i = t; i < KCAP; i += 256) counts[rb * KCAP + i] = hist[i];
    return;
  }

  // ---- tiled GEMM regions (input tile + W chunks staged in LDS) ----
  const float* IN; const float* W; int valid; int r0 = rb * 32;
  if (region == 0)      { IN = hidden; W = Wh; valid = MR; }
  else if (region == 1) { IN = rela;   W = Wh; valid = NR2; }
  else if (region == 2) { IN = hidden; W = Ws; valid = MR; }
  else if (region == 3) { IN = rela;   W = Wr; valid = NR2; }
  else                  { IN = rela;   W = Wr; valid = n_rel; r0 = NR2 + rb * 32; }

  const float4* in4 = (const float4*)IN;
  for (int i = t; i < 32 * 32; i += 256) {
    int row = i >> 5, q = i & 31;
    int gr = r0 + row;
    float4 v = make_float4(0.f, 0.f, 0.f, 0.f);
    if (gr < valid) v = in4[(size_t)gr * 32 + q];
    smem[i] = v;
  }
  int cg = t & 31, rg = t >> 5;
  const float4* W4 = (const float4*)W;
  const float* sh = (const float*)smem;
  const float* shW = (const float*)smemW;
  float4 a0{0,0,0,0}, a1{0,0,0,0}, a2{0,0,0,0}, a3{0,0,0,0};
  for (int kc = 0; kc < 4; ++kc) {
    __syncthreads();   // protects smemW reuse; first pass also covers input staging
    for (int i = t; i < 32 * 32; i += 256) smemW[i] = W4[(size_t)(kc * 32) * 32 + i];
    __syncthreads();
#pragma unroll 8
    for (int k2 = 0; k2 < 32; ++k2) {
      int k = kc * 32 + k2;
      float4 tv = *(const float4*)&shW[k2 * DIM + cg * 4];
      float s0 = sh[(rg * 4 + 0) * DIM + k];
      float s1 = sh[(rg * 4 + 1) * DIM + k];
      float s2 = sh[(rg * 4 + 2) * DIM + k];
      float s3 = sh[(rg * 4 + 3) * DIM + k];
      a0.x += s0 * tv.x; a0.y += s0 * tv.y; a0.z += s0 * tv.z; a0.w += s0 * tv.w;
      a1.x += s1 * tv.x; a1.y += s1 * tv.y; a1.z += s1 * tv.z; a1.w += s1 * tv.w;
      a2.x += s2 * tv.x; a2.y += s2 * tv.y; a2.z += s2 * tv.z; a2.w += s2 * tv.w;
      a3.x += s3 * tv.x; a3.y += s3 * tv.y; a3.z += s3 * tv.z; a3.w += s3 * tv.w;
    }
  }
  float4 accs[4] = {a0, a1, a2, a3};
  if (region <= 1) {
    float4* O4 = (float4*)(region == 0 ? T : T + (size_t)KCAP * DIM);
#pragma unroll
    for (int j = 0; j < 4; ++j) O4[(size_t)(r0 + rg * 4 + j) * 32 + cg] = accs[j];
    return;
  }
  if (region == 2) {  // P1 -> half
    H2x2* O = (H2x2*)P1h;
#pragma unroll
    for (int j = 0; j < 4; ++j) O[(size_t)(r0 + rg * 4 + j) * 32 + cg] = pack4(accs[j]);
    return;
  }
  if (region == 4) {  // P2 tail f32
    float4* P24 = (float4*)P2;
#pragma unroll
    for (int j = 0; j < 4; ++j) P24[(size_t)(r0 + rg * 4 + j) * 32 + cg] = accs[j];
    return;
  }
  // region 3: C4 recompute via LDS-chunked Wkg, write P2 f32 + P2Ch half (+C4 from block 0)
  float4 S0{0,0,0,0}, S1{0,0,0,0}, S0p{0,0,0,0}, S1p{0,0,0,0};
  const float4* Wk4 = (const float4*)Wkg;
  for (int kc = 0; kc < 8; ++kc) {
    __syncthreads();
    for (int i = t; i < 32 * 32; i += 256) smemW[i] = Wk4[(size_t)(kc * 32) * 32 + i];
    __syncthreads();
    if (kc < 4) {
#pragma unroll 8
      for (int k2 = 0; k2 < 32; ++k2) {
        int kk = kc * 32 + k2;
        float kg0 = kg[kk], kg1 = kg[DIM + kk];
        float4 w = *(const float4*)&shW[k2 * DIM + cg * 4];
        S0.x += kg0 * w.x; S0.y += kg0 * w.y; S0.z += kg0 * w.z; S0.w += kg0 * w.w;
        S1.x += kg1 * w.x; S1.y += kg1 * w.y; S1.z += kg1 * w.z; S1.w += kg1 * w.w;
      }
    } else {
#pragma unroll 8
      for (int k2 = 0; k2 < 32; ++k2) {
        int kk = (kc - 4) * 32 + k2;
        float kg0 = kg[kk], kg1 = kg[DIM + kk];
        float4 w = *(const float4*)&shW[k2 * DIM + cg * 4];
        S0p.x += kg0 * w.x; S0p.y += kg0 * w.y; S0p.z += kg0 * w.z; S0p.w += kg0 * w.w;
        S1p.x += kg1 * w.x; S1p.y += kg1 * w.y; S1p.z += kg1 * w.z; S1p.w += kg1 * w.w;
      }
    }
  }
  float4 b4 = ((const float4*)Wkg_b)[cg];
  float4 c4v[4];
  c4v[0] = make_float4(b4.x + S0.x + S0p.x, b4.y + S0.y + S0p.y, b4.z + S0.z + S0p.z, b4.w + S0.w + S0p.w);
  c4v[1] = make_float4(b4.x + S0.x + S1p.x, b4.y + S0.y + S1p.y, b4.z + S0.z + S1p.z, b4.w + S0.w + S1p.w);
  c4v[2] = make_float4(b4.x + S1.x + S0p.x, b4.y + S1.y + S0p.y, b4.z + S1.z + S0p.z, b4.w + S1.w + S0p.w);
  c4v[3] = make_float4(b4.x + S1.x + S1p.x, b4.y + S1.y + S1p.y, b4.z + S1.z + S1p.z, b4.w + S1.w + S1p.w);
  if (rb == 0 && rg == 0) {  // free C4 write for k_fallback (was the 40us serial block)
    float4* C44 = (float4*)C4;
#pragma unroll
    for (int c = 0; c < 4; ++c) C44[c * 32 + cg] = c4v[c];
  }
  float4* P24 = (float4*)P2;
  H2x2* PC = (H2x2*)P2Ch;
#pragma unroll
  for (int j = 0; j < 4; ++j) {
    int row = r0 + rg * 4 + j;
    float4 a = accs[j];
    P24[(size_t)row * 32 + cg] = a;
#pragma unroll
    for (int c = 0; c < 4; ++c) {
      float4 v = make_float4(a.x + c4v[c].x, a.y + c4v[c].y, a.z + c4v[c].z, a.w + c4v[c].w);
      PC[((size_t)row * 4 + c) * 32 + cg] = pack4(v);
    }
  }
}

// ======= per-edge alpha — packed fp16, 8 lanes/edge (2x edges in flight) =======
__global__ __launch_bounds__(256, 4) void k_alpha(
    const int* __restrict__ edges, int n_edge,
    const _Float16* __restrict__ P1h, const _Float16* __restrict__ P2Ch,
    const float* __restrict__ w_alpha, const float* __restrict__ w_alpha_b,
    const int* __restrict__ left_ptr, uint2* __restrict__ pa,
    int* __restrict__ fb_list, int* __restrict__ fb_count, int mr, int nr2) {
  __shared__ int seH[EPB];
  __shared__ int4 seQ[EPB];   // {rel, tail, sub, obj}
  int base = blockIdx.x * EPB;
  int cnt = n_edge - base; if (cnt > EPB) cnt = EPB;
  if (cnt <= 0) return;
  for (int i = threadIdx.x; i < cnt; i += 256) {
    const int* ep = edges + (long long)(base + i) * 6;
    int2 ph  = *(const int2*)ep;
    int2 prt = *(const int2*)(ep + 2);
    int2 pso = *(const int2*)(ep + 4);
    seH[i] = ph.y;
    seQ[i] = make_int4(prt.x, prt.y, pso.x, pso.y);
  }
  __syncthreads();
  int g = threadIdx.x >> 3;   // 32 groups of 8 lanes
  int l = threadIdx.x & 7;
  int left = left_ptr[0];
  float wb = w_alpha_b[0];
  float4 wf0 = ((const float4*)w_alpha)[l * 4 + 0];
  float4 wf1 = ((const float4*)w_alpha)[l * 4 + 1];
  float4 wf2 = ((const float4*)w_alpha)[l * 4 + 2];
  float4 wf3 = ((const float4*)w_alpha)[l * 4 + 3];
  h2v wah0 = h2v{(_Float16)wf0.x, (_Float16)wf0.y};
  h2v wah1 = h2v{(_Float16)wf0.z, (_Float16)wf0.w};
  h2v wah2 = h2v{(_Float16)wf1.x, (_Float16)wf1.y};
  h2v wah3 = h2v{(_Float16)wf1.z, (_Float16)wf1.w};
  h2v wah4 = h2v{(_Float16)wf2.x, (_Float16)wf2.y};
  h2v wah5 = h2v{(_Float16)wf2.z, (_Float16)wf2.w};
  h2v wah6 = h2v{(_Float16)wf3.x, (_Float16)wf3.y};
  h2v wah7 = h2v{(_Float16)wf3.z, (_Float16)wf3.w};
  const h2v z2 = h2v{(_Float16)0.f, (_Float16)0.f};

  int i0 = g * EPG;
  int iend = i0 + EPG; if (iend > cnt) iend = cnt;
  if (i0 >= iend) return;

  int subA, relA, objA; bool okA; H2x4 paA0, paA1, pbA0, pbA1;
  int subB, relB, objB; bool okB; H2x4 paB0, paB1, pbB0, pbB1;

#define LOADI(i, rel_, sub_, obj_, ok_, pa0_, pa1_, pb0_, pb1_)                  \
  {                                                                              \
    int hh = seH[(i)];                                                           \
    int4 q = seQ[(i)];                                                           \
    rel_ = q.x; sub_ = q.z; obj_ = q.w;                                          \
    ok_ = (sub_ < mr) && (obj_ < mr) && (rel_ < nr2);                            \
    int c = ((hh >= left) ? 2 : 0) | ((q.y >= left) ? 1 : 0);                    \
    if (ok_) {                                                                   \
      const H2x4* p1 = (const H2x4*)(P1h + (size_t)sub_ * DIM);                  \
      const H2x4* p2 = (const H2x4*)(P2Ch + ((size_t)(rel_ * 4 + c)) * DIM);     \
      pa0_ = p1[l * 2]; pa1_ = p1[l * 2 + 1];                                    \
      pb0_ = p2[l * 2]; pb1_ = p2[l * 2 + 1];                                    \
    } else if (l == 0) {                                                         \
      int pos = atomicAdd(fb_count, 1);                                          \
      fb_list[pos] = base + (i);                                                 \
      pa[base + (i)] = make_uint2(0xFFFFFFFFu, 0u);                              \
    }                                                                            \
  }

#define COMP(i, rel_, sub_, obj_, ok_, pa0_, pa1_, pb0_, pb1_)                   \
  if (ok_) {                                                                     \
    h2v acc = __builtin_elementwise_max(pa0_.h0 + pb0_.h0, z2) * wah0;           \
    acc += __builtin_elementwise_max(pa0_.h1 + pb0_.h1, z2) * wah1;              \
    acc += __builtin_elementwise_max(pa0_.h2 + pb0_.h2, z2) * wah2;              \
    acc += __builtin_elementwise_max(pa0_.h3 + pb0_.h3, z2) * wah3;              \
    acc += __builtin_elementwise_max(pa1_.h0 + pb1_.h0, z2) * wah4;              \
    acc += __builtin_elementwise_max(pa1_.h1 + pb1_.h1, z2) * wah5;              \
    acc += __builtin_elementwise_max(pa1_.h2 + pb1_.h2, z2) * wah6;              \
    acc += __builtin_elementwise_max(pa1_.h3 + pb1_.h3, z2) * wah7;              \
    float s = (float)acc[0] + (float)acc[1];                                     \
    s += __shfl_xor(s, 1); s += __shfl_xor(s, 2); s += __shfl_xor(s, 4);         \
    if (l == 0) {                                                                \
      float av = 1.f / (1.f + expf(-(s + wb)));                                  \
      unsigned pk = (unsigned)sub_ | ((unsigned)rel_ << 10) | ((unsigned)obj_ << 20); \
      pa[base + (i)] = make_uint2(pk, __float_as_uint(av));                      \
    }                                                                            \
  }

  int icur = i0;
  LOADI(icur, relA, subA, objA, okA, paA0, paA1, pbA0, pbA1);
  for (;;) {
    int inext = icur + 1;
    bool hasNext = inext < iend;
    if (hasNext) LOADI(inext, relB, subB, objB, okB, paB0, paB1, pbB0, pbB1);
    COMP(icur, relA, subA, objA, okA, paA0, paA1, pbA0, pbA1);
    if (!hasNext) break;
    icur = inext;
    int inn = icur + 1;
    bool h2 = inn < iend;
    if (h2) LOADI(inn, relA, subA, objA, okA, paA0, paA1, pbA0, pbA1);
    COMP(icur, relB, subB, objB, okB, paB0, paB1, pbB0, pbB1);
    if (!h2) break;
    icur = inn;
  }
#undef LOADI
#undef COMP
}

// ============ contention-free scatter: in-prologue scan + LDS cursors ============
__global__ __launch_bounds__(256) void k_scatter(const uint2* __restrict__ pa, int n_edge,
                                                 int eps, const int* __restrict__ counts,
                                                 uint2* __restrict__ sorted,
                                                 int* __restrict__ off) {
  __shared__ int curs[KCAP];
  __shared__ int tot[KCAP];
  __shared__ int wsum[256];
  int b = blockIdx.x;
  int t = threadIdx.x;
  {
    int o0 = t * 4;
    int tt0 = 0, tt1 = 0, tt2 = 0, tt3 = 0;
    int pb0 = 0, pb1 = 0, pb2 = 0, pb3 = 0;
    for (int bb = 0; bb < NB_SORT; ++bb) {
      const int* row = counts + bb * KCAP + o0;
      int c0 = row[0], c1 = row[1], c2 = row[2], c3 = row[3];
      tt0 += c0; tt1 += c1; tt2 += c2; tt3 += c3;
      if (bb < b) { pb0 += c0; pb1 += c1; pb2 += c2; pb3 += c3; }
    }
    tot[o0] = tt0; tot[o0 + 1] = tt1; tot[o0 + 2] = tt2; tot[o0 + 3] = tt3;
    curs[o0] = pb0; curs[o0 + 1] = pb1; curs[o0 + 2] = pb2; curs[o0 + 3] = pb3;
  }
  __syncthreads();
  int o0 = t * 4;
  int s0 = tot[o0], s1 = tot[o0 + 1], s2 = tot[o0 + 2], s3 = tot[o0 + 3];
  wsum[t] = s0 + s1 + s2 + s3;
  __syncthreads();
  for (int d = 1; d < 256; d <<= 1) {
    int x = (t >= d) ? wsum[t - d] : 0;
    __syncthreads();
    wsum[t] += x;
    __syncthreads();
  }
  int run = (t > 0) ? wsum[t - 1] : 0;
  curs[o0]     += run;
  curs[o0 + 1] += run + s0;
  curs[o0 + 2] += run + s0 + s1;
  curs[o0 + 3] += run + s0 + s1 + s2;
  if (b == 0) {
    off[o0] = run;
    off[o0 + 1] = run + s0;
    off[o0 + 2] = run + s0 + s1;
    off[o0 + 3] = run + s0 + s1 + s2;
    if (t == 255) off[KCAP] = wsum[255];
  }
  __syncthreads();
  int s = b * eps;
  int e = s + eps; if (e > n_edge) e = n_edge;
  for (int i = s + t; i < e; i += 256) {
    uint2 v = pa[i];
    if (v.x == 0xFFFFFFFFu) continue;
    int o = (v.x >> 20) & (KCAP - 1);
    int slot = atomicAdd(&curs[o], 1);
    sorted[slot] = v;
  }
}

// ============ per-obj LDS accumulation -> dense AB row ============
__global__ __launch_bounds__(256) void k_agg(const uint2* __restrict__ sorted,
                                             const int* __restrict__ off,
                                             float* __restrict__ AB) {
  __shared__ float coef[CW];
  int o = blockIdx.x;
  for (int i = threadIdx.x; i < CW; i += 256) coef[i] = 0.f;
  __syncthreads();
  int s = off[o], e = off[o + 1];
  for (int i = s + threadIdx.x; i < e; i += 256) {
    uint2 v = sorted[i];
    float a = __uint_as_float(v.y);
    atomicAdd(&coef[v.x & (KCAP - 1)], a);
    atomicAdd(&coef[KCAP + ((v.x >> 10) & (KCAP - 1))], a);
  }
  __syncthreads();
  float4* abr = (float4*)(AB + (size_t)o * CW);
  for (int i = threadIdx.x; i < CW / 4; i += 256) abr[i] = ((const float4*)coef)[i];
}

// ============ split-K GEMM (tail-zero lives in k_pre) ============
__global__ __launch_bounds__(512) void k_gemm2(const float* __restrict__ AB,
                                               const float* __restrict__ T,
                                               float* __restrict__ part) {
  __shared__ float sh[MT2][KCH2 + 4];
  int mt = blockIdx.x / NKC2;
  int kc = blockIdx.x % NKC2;
  int m0 = mt * MT2, k0 = kc * KCH2;
  for (int i = threadIdx.x; i < MT2 * (KCH2 / 4); i += 512) {
    int r = i >> 5, kq = i & 31;
    *(float4*)&sh[r][kq * 4] = *(const float4*)(AB + (long long)(m0 + r) * CW + k0 + kq * 4);
  }
  __syncthreads();
  int cg = threadIdx.x & 31;
  int rg = threadIdx.x >> 5;
  const float4* T4 = (const float4*)T;
  float4 acc0 = {0,0,0,0}, acc1 = {0,0,0,0}, acc2 = {0,0,0,0}, acc3 = {0,0,0,0};
#pragma unroll 4
  for (int k = 0; k < KCH2; ++k) {
    float4 tv = T4[(long long)(k0 + k) * (DIM / 4) + cg];
    float a0 = sh[rg * 4 + 0][k];
    float a1 = sh[rg * 4 + 1][k];
    float a2 = sh[rg * 4 + 2][k];
    float a3 = sh[rg * 4 + 3][k];
    acc0.x += a0 * tv.x; acc0.y += a0 * tv.y; acc0.z += a0 * tv.z; acc0.w += a0 * tv.w;
    acc1.x += a1 * tv.x; acc1.y += a1 * tv.y; acc1.z += a1 * tv.z; acc1.w += a1 * tv.w;
    acc2.x += a2 * tv.x; acc2.y += a2 * tv.y; acc2.z += a2 * tv.z; acc2.w += a2 * tv.w;
    acc3.x += a3 * tv.x; acc3.y += a3 * tv.y; acc3.z += a3 * tv.z; acc3.w += a3 * tv.w;
  }
  float4* p = (float4*)(part + ((long long)kc * KCAP + m0 + rg * 4) * DIM) + cg;
  p[0 * (DIM / 4)] = acc0;
  p[1 * (DIM / 4)] = acc1;
  p[2 * (DIM / 4)] = acc2;
  p[3 * (DIM / 4)] = acc3;
}

// ============ reduce partials (live rows only) -> out ============
__global__ void k_outfin(const float* __restrict__ part, float* __restrict__ out, int MR) {
  long long total = (long long)MR * 32;
  long long i = (long long)blockIdx.x * blockDim.x + threadIdx.x;
  long long stride = (long long)gridDim.x * blockDim.x;
  const float4* p4 = (const float4*)part;
  float4* o4 = (float4*)out;
  for (; i < total; i += stride) {
    long long r = i >> 5;
    int c4 = (int)(i & 31);
    float4 v = {0.f, 0.f, 0.f, 0.f};
#pragma unroll
    for (int kc = 0; kc < NKC2; ++kc) {
      float4 t = p4[((long long)kc * KCAP + r) * 32 + c4];
      v.x += t.x; v.y += t.y; v.z += t.z; v.w += t.w;
    }
    o4[i] = v;
  }
}

// ============ general fallback: one wave per listed edge, adds onto out ============
__global__ void k_fallback(const int* __restrict__ edges, const float* __restrict__ hidden,
                           const float* __restrict__ rela, const float* __restrict__ P2,
                           const float* __restrict__ C4, const float* __restrict__ Ws,
                           const float* __restrict__ w_alpha, const float* __restrict__ w_alpha_b,
                           const float* __restrict__ Wh, const int* __restrict__ left_ptr,
                           const int* __restrict__ fb_list, const int* __restrict__ fb_count,
                           float* __restrict__ out) {
  int nfb = fb_count[0];
  if (nfb == 0) return;
  int wave = (blockIdx.x * blockDim.x + threadIdx.x) >> 6;
  int nw = (gridDim.x * blockDim.x) >> 6;
  int lane = threadIdx.x & 63;
  int left = left_ptr[0];
  for (int i = wave; i < nfb; i += nw) {
    int e = fb_list[i];
    int head = edges[(long long)e * 6 + 1];
    int rel  = edges[(long long)e * 6 + 2];
    int tail = edges[(long long)e * 6 + 3];
    int sub  = edges[(long long)e * 6 + 4];
    int obj  = edges[(long long)e * 6 + 5];
    int c = ((head >= left) ? 2 : 0) | ((tail >= left) ? 1 : 0);
    float pre0 = P2[(long long)rel * DIM + lane] + C4[c * DIM + lane];
    float pre1 = P2[(long long)rel * DIM + 64 + lane] + C4[c * DIM + 64 + lane];
    for (int k = 0; k < DIM; ++k) {
      float h = hidden[(long long)sub * DIM + k];
      pre0 += h * Ws[k * DIM + lane];
      pre1 += h * Ws[k * DIM + 64 + lane];
    }
    float s = fmaxf(pre0, 0.f) * w_alpha[lane] + fmaxf(pre1, 0.f) * w_alpha[64 + lane];
    for (int d = 1; d < 64; d <<= 1) s += __shfl_xor(s, d);
    float alpha = 1.f / (1.f + expf(-(s + w_alpha_b[0])));
    float o0 = 0.f, o1 = 0.f;
    for (int k = 0; k < DIM; ++k) {
      float m = hidden[(long long)sub * DIM + k] + rela[(long long)rel * DIM + k];
      o0 += m * Wh[k * DIM + lane];
      o1 += m * Wh[k * DIM + 64 + lane];
    }
    atomicAdd(&out[(long long)obj * DIM + lane], alpha * o0);
    atomicAdd(&out[(long long)obj * DIM + 64 + lane], alpha * o1);
  }
}

extern "C" void kernel_launch(void* const* d_in, const int* in_sizes, int n_in,
                              void* d_out, int out_size, void* d_ws, size_t ws_size,
                              hipStream_t stream) {
  const float* hidden    = (const float*)d_in[0];
  const int*   edges     = (const int*)d_in[1];
  const float* kg_table  = (const float*)d_in[2];
  const float* rela      = (const float*)d_in[3];
  const float* Ws        = (const float*)d_in[4];
  const float* Wr        = (const float*)d_in[5];
  const float* Wkg_w     = (const float*)d_in[6];
  const float* Wkg_b     = (const float*)d_in[7];
  const float* w_alpha   = (const float*)d_in[8];
  const float* w_alpha_b = (const float*)d_in[9];
  const float* Wh        = (const float*)d_in[10];
  const int*   left_ptr  = (const int*)d_in[12];

  int n_node = out_size / DIM;
  int n_edge = in_sizes[1] / 6;
  int n_rel  = in_sizes[3] / DIM;
  int MR  = n_node < KCAP ? n_node : KCAP;
  int NR2 = n_rel < KCAP ? n_rel : KCAP;
  int eps = (n_edge + NB_SORT - 1) / NB_SORT;

  int nbA   = KCAP / 32;                               // 32
  int nbP2C = (NR2 + 31) / 32;
  int nbD   = (n_rel > NR2) ? (n_rel - NR2 + 31) / 32 : 0;
  int n_relpad = ((n_rel + 31) / 32) * 32;
  int NR2pad   = nbP2C * 32;

  char* ws = (char*)d_ws;
  size_t o = 0;
  auto alloc = [&](size_t b) { size_t r = o; o += (b + 255) & ~(size_t)255; return r; };
  float*    AB       = (float*)(ws + alloc((size_t)KCAP * CW * 4));           // 8 MB
  float*    T        = (float*)(ws + alloc((size_t)CW * DIM * 4));            // 1 MB
  _Float16* P1h      = (_Float16*)(ws + alloc((size_t)KCAP * DIM * 2));       // 256 KB
  float*    P2       = (float*)(ws + alloc((size_t)n_relpad * DIM * 4));
  _Float16* P2Ch     = (_Float16*)(ws + alloc((size_t)NR2pad * 4 * DIM * 2)); // 1 MB
  float*    C4       = (float*)(ws + alloc(4 * DIM * 4));
  float*    part     = (float*)(ws + alloc((size_t)NKC2 * KCAP * DIM * 4));   // 8 MB
  uint2*    pa       = (uint2*)(ws + alloc((size_t)n_edge * 8));              // 5 MB
  uint2*    sorted   = (uint2*)(ws + alloc((size_t)n_edge * 8));              // 5 MB
  int*      counts   = (int*)(ws + alloc((size_t)NB_SORT * KCAP * 4));        // 512 KB
  int*      off      = (int*)(ws + alloc((size_t)(KCAP + 1) * 4));
  int*      fb_list  = (int*)(ws + alloc((size_t)n_edge * 4));
  int*      fb_count = (int*)(ws + alloc(4));
  float*    out  = (float*)d_out;

  // fused precompute + histogram + out-tail-zero (one dispatch, multi-region)
  int nblocks = 3 * nbA + nbP2C + nbD + 1 + NB_SORT + NTZ;
  k_pre<<<nblocks, 256, 0, stream>>>(
      hidden, rela, kg_table, Ws, Wr, Wh, Wkg_w, Wkg_b, edges, n_edge, eps,
      P1h, P2, P2Ch, T, C4, counts, fb_count, out, n_node,
      MR, n_rel, NR2, nbA, nbP2C, nbD);

  // alpha + packed payload (fp16 packed math, 8 lanes/edge)
  int nb = (n_edge + EPB - 1) / EPB;
  k_alpha<<<nb, 256, 0, stream>>>(edges, n_edge, P1h, P2Ch, w_alpha, w_alpha_b,
                                  left_ptr, pa, fb_list, fb_count, MR, NR2);

  // counting-sort scatter (LDS cursors)
  k_scatter<<<NB_SORT, 256, 0, stream>>>(pa, n_edge, eps, counts, sorted, off);

  // per-obj LDS accumulation -> dense AB rows
  k_agg<<<KCAP, 256, 0, stream>>>(sorted, off, AB);

  // split-K GEMM into partials, then reduce live rows
  k_gemm2<<<NGEMM, 512, 0, stream>>>(AB, T, part);
  k_outfin<<<256, 256, 0, stream>>>(part, out, MR);

  // general-index fallback (empty for this dataset)
  k_fallback<<<64, 256, 0, stream>>>(edges, hidden, rela, P2, C4, Ws, w_alpha,
                                     w_alpha_b, Wh, left_ptr, fb_list, fb_count, out);
}

// Round 15
// 105.122 us; speedup vs baseline: 1.1050x; 1.1050x over previous
//
#include <hip/hip_runtime.h>
#include <math.h>

#define DIM   128
#define KCAP  1024   // dense cap for sub/obj/rel indices (each fits 10 bits)
#define CW    2048   // AB row width: [0,KCAP)=sub coeffs, [KCAP,2*KCAP)=rel coeffs
#define EPG   10     // edges per 8-lane group in k_alpha
#define EPB   (EPG * 32)   // 320 edges per k_alpha block
#define MT2   64     // M-tile rows per k_gemm2 block
#define KCH2  128    // K-chunk
#define NKC2  (CW / KCH2)   // 16
#define NGEMM ((KCAP / MT2) * NKC2)  // 256
#define NTZ   1024   // tail-zero blocks appended to k_pre
#define NB_SORT 128  // blocks in hist/scatter (must match)

typedef _Float16 h2v __attribute__((ext_vector_type(2)));
struct __align__(8)  H2x2 { h2v a, b; };
struct __align__(16) H2x4 { h2v h0, h1, h2, h3; };
__device__ inline H2x2 pack4(float4 v) {
  H2x2 r;
  r.a = h2v{(_Float16)v.x, (_Float16)v.y};
  r.b = h2v{(_Float16)v.z, (_Float16)v.w};
  return r;
}

// ================== fused precompute (multi-region tiled GEMM) ==================
// Round-11 structure (best measured: 110.3us total) with ONE change: the serial
// C4 region (1 block, 64 lanes, 256 dependent global loads = ~40us straggler) is
// deleted; region 3 block 0 writes C4 from its already-computed c4v registers.
// regions: 0: T[0:1024]=hidden@Wh | 1: T[1024:2048]=rela@Wh | 2: P1h=half(hidden@Ws)
//          3: P2=rela@Wr + P2Ch[(rel,c)]=half(P2+C4); block0 writes C4
//          4: P2 tail f32 | 5: fb_count=0 | 6: obj histogram | 7: out tail-zero
__global__ __launch_bounds__(256) void k_pre(
    const float* __restrict__ hidden, const float* __restrict__ rela,
    const float* __restrict__ kg, const float* __restrict__ Ws,
    const float* __restrict__ Wr, const float* __restrict__ Wh,
    const float* __restrict__ Wkg, const float* __restrict__ Wkg_b,
    const int* __restrict__ edges, int n_edge, int eps,
    _Float16* __restrict__ P1h, float* __restrict__ P2, _Float16* __restrict__ P2Ch,
    float* __restrict__ T, float* __restrict__ C4,
    int* __restrict__ counts, int* __restrict__ fb_count,
    float* __restrict__ out, int n_node,
    int MR, int n_rel, int NR2, int nbA, int nbP2C, int nbD) {
  __shared__ float4 smem[32 * 32];  // 16 KB: input tile OR hist
  int t = threadIdx.x;
  int rb = blockIdx.x;
  int region;
  if (rb < nbA) region = 0;
  else if ((rb -= nbA) < nbA) region = 1;
  else if ((rb -= nbA) < nbA) region = 2;
  else if ((rb -= nbA) < nbP2C) region = 3;
  else if ((rb -= nbP2C) < nbD) region = 4;
  else if ((rb -= nbD) < 1) region = 5;
  else if ((rb -= 1) < NB_SORT) region = 6;
  else { rb -= NB_SORT; region = 7; }

  if (region == 7) {  // out tail-zero: rows [MR, n_node)
    long long s = (long long)MR * 32;
    long long tot = (long long)n_node * 32;
    long long i = s + (long long)rb * 256 + t;
    long long stride = (long long)NTZ * 256;
    float4 z{0.f, 0.f, 0.f, 0.f};
    float4* o4 = (float4*)out;
    for (; i < tot; i += stride) o4[i] = z;
    return;
  }
  if (region == 5) {  // fb_count zero only (C4 written by region 3 block 0)
    if (t == 0) *fb_count = 0;
    return;
  }
  if (region == 6) {  // per-block obj histogram -> counts[rb][o] (coalesced)
    int* hist = (int*)smem;
    for (int i = t; i < KCAP; i += 256) hist[i] = 0;
    __syncthreads();
    int s = rb * eps;
    int e = s + eps; if (e > n_edge) e = n_edge;
    for (int i = s + t; i < e; i += 256) {
      int rel = edges[(long long)i * 6 + 2];
      int2 so = *(const int2*)(edges + (long long)i * 6 + 4);
      if (so.x < MR && so.y < MR && rel < NR2) atomicAdd(&hist[so.y], 1);
    }
    __syncthreads();
    for (int i = t; i < KCAP; i += 256) counts[rb * KCAP + i] = hist[i];
    return;
  }

  // ---- tiled GEMM regions (direct global W loads — the chunked variant regressed) ----
  const float* IN; const float* W; int valid; int r0 = rb * 32;
  if (region == 0)      { IN = hidden; W = Wh; valid = MR; }
  else if (region == 1) { IN = rela;   W = Wh; valid = NR2; }
  else if (region == 2) { IN = hidden; W = Ws; valid = MR; }
  else if (region == 3) { IN = rela;   W = Wr; valid = NR2; }
  else                  { IN = rela;   W = Wr; valid = n_rel; r0 = NR2 + rb * 32; }

  const float4* in4 = (const float4*)IN;
  for (int i = t; i < 32 * 32; i += 256) {
    int row = i >> 5, q = i & 31;
    int gr = r0 + row;
    float4 v = make_float4(0.f, 0.f, 0.f, 0.f);
    if (gr < valid) v = in4[(size_t)gr * 32 + q];
    smem[i] = v;
  }
  __syncthreads();
  int cg = t & 31, rg = t >> 5;
  const float4* W4 = (const float4*)W;
  const float* sh = (const float*)smem;
  float4 a0{0,0,0,0}, a1{0,0,0,0}, a2{0,0,0,0}, a3{0,0,0,0};
#pragma unroll 8
  for (int k = 0; k < DIM; ++k) {
    float4 tv = W4[k * 32 + cg];
    float s0 = sh[(rg * 4 + 0) * DIM + k];
    float s1 = sh[(rg * 4 + 1) * DIM + k];
    float s2 = sh[(rg * 4 + 2) * DIM + k];
    float s3 = sh[(rg * 4 + 3) * DIM + k];
    a0.x += s0 * tv.x; a0.y += s0 * tv.y; a0.z += s0 * tv.z; a0.w += s0 * tv.w;
    a1.x += s1 * tv.x; a1.y += s1 * tv.y; a1.z += s1 * tv.z; a1.w += s1 * tv.w;
    a2.x += s2 * tv.x; a2.y += s2 * tv.y; a2.z += s2 * tv.z; a2.w += s2 * tv.w;
    a3.x += s3 * tv.x; a3.y += s3 * tv.y; a3.z += s3 * tv.z; a3.w += s3 * tv.w;
  }
  float4 accs[4] = {a0, a1, a2, a3};
  if (region <= 1) {
    float4* O4 = (float4*)(region == 0 ? T : T + (size_t)KCAP * DIM);
#pragma unroll
    for (int j = 0; j < 4; ++j) O4[(size_t)(r0 + rg * 4 + j) * 32 + cg] = accs[j];
    return;
  }
  if (region == 2) {  // P1 -> half
    H2x2* O = (H2x2*)P1h;
#pragma unroll
    for (int j = 0; j < 4; ++j) O[(size_t)(r0 + rg * 4 + j) * 32 + cg] = pack4(accs[j]);
    return;
  }
  if (region == 4) {  // P2 tail f32
    float4* P24 = (float4*)P2;
#pragma unroll
    for (int j = 0; j < 4; ++j) P24[(size_t)(r0 + rg * 4 + j) * 32 + cg] = accs[j];
    return;
  }
  // region 3: inline C4 recompute (direct loads, as rounds 7-11), write P2 + P2Ch (+C4)
  float4 S0{0,0,0,0}, S1{0,0,0,0}, S0p{0,0,0,0}, S1p{0,0,0,0};
  const float4* Wk4 = (const float4*)Wkg;
#pragma unroll 8
  for (int k = 0; k < DIM; ++k) {
    float kg0 = kg[k], kg1 = kg[DIM + k];
    float4 w0 = Wk4[k * 32 + cg];
    float4 w1 = Wk4[(DIM + k) * 32 + cg];
    S0.x += kg0 * w0.x; S0.y += kg0 * w0.y; S0.z += kg0 * w0.z; S0.w += kg0 * w0.w;
    S1.x += kg1 * w0.x; S1.y += kg1 * w0.y; S1.z += kg1 * w0.z; S1.w += kg1 * w0.w;
    S0p.x += kg0 * w1.x; S0p.y += kg0 * w1.y; S0p.z += kg0 * w1.z; S0p.w += kg0 * w1.w;
    S1p.x += kg1 * w1.x; S1p.y += kg1 * w1.y; S1p.z += kg1 * w1.z; S1p.w += kg1 * w1.w;
  }
  float4 b4 = ((const float4*)Wkg_b)[cg];
  float4 c4v[4];
  c4v[0] = make_float4(b4.x + S0.x + S0p.x, b4.y + S0.y + S0p.y, b4.z + S0.z + S0p.z, b4.w + S0.w + S0p.w);
  c4v[1] = make_float4(b4.x + S0.x + S1p.x, b4.y + S0.y + S1p.y, b4.z + S0.z + S1p.z, b4.w + S0.w + S1p.w);
  c4v[2] = make_float4(b4.x + S1.x + S0p.x, b4.y + S1.y + S0p.y, b4.z + S1.z + S0p.z, b4.w + S1.w + S0p.w);
  c4v[3] = make_float4(b4.x + S1.x + S1p.x, b4.y + S1.y + S1p.y, b4.z + S1.z + S1p.z, b4.w + S1.w + S1p.w);
  if (rb == 0 && rg == 0) {  // C4 for k_fallback — free from registers
    float4* C44 = (float4*)C4;
#pragma unroll
    for (int c = 0; c < 4; ++c) C44[c * 32 + cg] = c4v[c];
  }
  float4* P24 = (float4*)P2;
  H2x2* PC = (H2x2*)P2Ch;
#pragma unroll
  for (int j = 0; j < 4; ++j) {
    int row = r0 + rg * 4 + j;
    float4 a = accs[j];
    P24[(size_t)row * 32 + cg] = a;
#pragma unroll
    for (int c = 0; c < 4; ++c) {
      float4 v = make_float4(a.x + c4v[c].x, a.y + c4v[c].y, a.z + c4v[c].z, a.w + c4v[c].w);
      PC[((size_t)row * 4 + c) * 32 + cg] = pack4(v);
    }
  }
}

// ======= per-edge alpha — packed fp16, 8 lanes/edge (2x edges in flight) =======
__global__ __launch_bounds__(256, 4) void k_alpha(
    const int* __restrict__ edges, int n_edge,
    const _Float16* __restrict__ P1h, const _Float16* __restrict__ P2Ch,
    const float* __restrict__ w_alpha, const float* __restrict__ w_alpha_b,
    const int* __restrict__ left_ptr, uint2* __restrict__ pa,
    int* __restrict__ fb_list, int* __restrict__ fb_count, int mr, int nr2) {
  __shared__ int seH[EPB];
  __shared__ int4 seQ[EPB];   // {rel, tail, sub, obj}
  int base = blockIdx.x * EPB;
  int cnt = n_edge - base; if (cnt > EPB) cnt = EPB;
  if (cnt <= 0) return;
  for (int i = threadIdx.x; i < cnt; i += 256) {
    const int* ep = edges + (long long)(base + i) * 6;
    int2 ph  = *(const int2*)ep;
    int2 prt = *(const int2*)(ep + 2);
    int2 pso = *(const int2*)(ep + 4);
    seH[i] = ph.y;
    seQ[i] = make_int4(prt.x, prt.y, pso.x, pso.y);
  }
  __syncthreads();
  int g = threadIdx.x >> 3;   // 32 groups of 8 lanes
  int l = threadIdx.x & 7;
  int left = left_ptr[0];
  float wb = w_alpha_b[0];
  float4 wf0 = ((const float4*)w_alpha)[l * 4 + 0];
  float4 wf1 = ((const float4*)w_alpha)[l * 4 + 1];
  float4 wf2 = ((const float4*)w_alpha)[l * 4 + 2];
  float4 wf3 = ((const float4*)w_alpha)[l * 4 + 3];
  h2v wah0 = h2v{(_Float16)wf0.x, (_Float16)wf0.y};
  h2v wah1 = h2v{(_Float16)wf0.z, (_Float16)wf0.w};
  h2v wah2 = h2v{(_Float16)wf1.x, (_Float16)wf1.y};
  h2v wah3 = h2v{(_Float16)wf1.z, (_Float16)wf1.w};
  h2v wah4 = h2v{(_Float16)wf2.x, (_Float16)wf2.y};
  h2v wah5 = h2v{(_Float16)wf2.z, (_Float16)wf2.w};
  h2v wah6 = h2v{(_Float16)wf3.x, (_Float16)wf3.y};
  h2v wah7 = h2v{(_Float16)wf3.z, (_Float16)wf3.w};
  const h2v z2 = h2v{(_Float16)0.f, (_Float16)0.f};

  int i0 = g * EPG;
  int iend = i0 + EPG; if (iend > cnt) iend = cnt;
  if (i0 >= iend) return;

  int subA, relA, objA; bool okA; H2x4 paA0, paA1, pbA0, pbA1;
  int subB, relB, objB; bool okB; H2x4 paB0, paB1, pbB0, pbB1;

#define LOADI(i, rel_, sub_, obj_, ok_, pa0_, pa1_, pb0_, pb1_)                  \
  {                                                                              \
    int hh = seH[(i)];                                                           \
    int4 q = seQ[(i)];                                                           \
    rel_ = q.x; sub_ = q.z; obj_ = q.w;                                          \
    ok_ = (sub_ < mr) && (obj_ < mr) && (rel_ < nr2);                            \
    int c = ((hh >= left) ? 2 : 0) | ((q.y >= left) ? 1 : 0);                    \
    if (ok_) {                                                                   \
      const H2x4* p1 = (const H2x4*)(P1h + (size_t)sub_ * DIM);                  \
      const H2x4* p2 = (const H2x4*)(P2Ch + ((size_t)(rel_ * 4 + c)) * DIM);     \
      pa0_ = p1[l * 2]; pa1_ = p1[l * 2 + 1];                                    \
      pb0_ = p2[l * 2]; pb1_ = p2[l * 2 + 1];                                    \
    } else if (l == 0) {                                                         \
      int pos = atomicAdd(fb_count, 1);                                          \
      fb_list[pos] = base + (i);                                                 \
      pa[base + (i)] = make_uint2(0xFFFFFFFFu, 0u);                              \
    }                                                                            \
  }

#define COMP(i, rel_, sub_, obj_, ok_, pa0_, pa1_, pb0_, pb1_)                   \
  if (ok_) {                                                                     \
    h2v acc = __builtin_elementwise_max(pa0_.h0 + pb0_.h0, z2) * wah0;           \
    acc += __builtin_elementwise_max(pa0_.h1 + pb0_.h1, z2) * wah1;              \
    acc += __builtin_elementwise_max(pa0_.h2 + pb0_.h2, z2) * wah2;              \
    acc += __builtin_elementwise_max(pa0_.h3 + pb0_.h3, z2) * wah3;              \
    acc += __builtin_elementwise_max(pa1_.h0 + pb1_.h0, z2) * wah4;              \
    acc += __builtin_elementwise_max(pa1_.h1 + pb1_.h1, z2) * wah5;              \
    acc += __builtin_elementwise_max(pa1_.h2 + pb1_.h2, z2) * wah6;              \
    acc += __builtin_elementwise_max(pa1_.h3 + pb1_.h3, z2) * wah7;              \
    float s = (float)acc[0] + (float)acc[1];                                     \
    s += __shfl_xor(s, 1); s += __shfl_xor(s, 2); s += __shfl_xor(s, 4);         \
    if (l == 0) {                                                                \
      float av = 1.f / (1.f + expf(-(s + wb)));                                  \
      unsigned pk = (unsigned)sub_ | ((unsigned)rel_ << 10) | ((unsigned)obj_ << 20); \
      pa[base + (i)] = make_uint2(pk, __float_as_uint(av));                      \
    }                                                                            \
  }

  int icur = i0;
  LOADI(icur, relA, subA, objA, okA, paA0, paA1, pbA0, pbA1);
  for (;;) {
    int inext = icur + 1;
    bool hasNext = inext < iend;
    if (hasNext) LOADI(inext, relB, subB, objB, okB, paB0, paB1, pbB0, pbB1);
    COMP(icur, relA, subA, objA, okA, paA0, paA1, pbA0, pbA1);
    if (!hasNext) break;
    icur = inext;
    int inn = icur + 1;
    bool h2 = inn < iend;
    if (h2) LOADI(inn, relA, subA, objA, okA, paA0, paA1, pbA0, pbA1);
    COMP(icur, relB, subB, objB, okB, paB0, paB1, pbB0, pbB1);
    if (!h2) break;
    icur = inn;
  }
#undef LOADI
#undef COMP
}

// ============ contention-free scatter: in-prologue scan + LDS cursors ============
__global__ __launch_bounds__(256) void k_scatter(const uint2* __restrict__ pa, int n_edge,
                                                 int eps, const int* __restrict__ counts,
                                                 uint2* __restrict__ sorted,
                                                 int* __restrict__ off) {
  __shared__ int curs[KCAP];
  __shared__ int tot[KCAP];
  __shared__ int wsum[256];
  int b = blockIdx.x;
  int t = threadIdx.x;
  {
    int o0 = t * 4;
    int tt0 = 0, tt1 = 0, tt2 = 0, tt3 = 0;
    int pb0 = 0, pb1 = 0, pb2 = 0, pb3 = 0;
    for (int bb = 0; bb < NB_SORT; ++bb) {
      const int* row = counts + bb * KCAP + o0;
      int c0 = row[0], c1 = row[1], c2 = row[2], c3 = row[3];
      tt0 += c0; tt1 += c1; tt2 += c2; tt3 += c3;
      if (bb < b) { pb0 += c0; pb1 += c1; pb2 += c2; pb3 += c3; }
    }
    tot[o0] = tt0; tot[o0 + 1] = tt1; tot[o0 + 2] = tt2; tot[o0 + 3] = tt3;
    curs[o0] = pb0; curs[o0 + 1] = pb1; curs[o0 + 2] = pb2; curs[o0 + 3] = pb3;
  }
  __syncthreads();
  int o0 = t * 4;
  int s0 = tot[o0], s1 = tot[o0 + 1], s2 = tot[o0 + 2], s3 = tot[o0 + 3];
  wsum[t] = s0 + s1 + s2 + s3;
  __syncthreads();
  for (int d = 1; d < 256; d <<= 1) {
    int x = (t >= d) ? wsum[t - d] : 0;
    __syncthreads();
    wsum[t] += x;
    __syncthreads();
  }
  int run = (t > 0) ? wsum[t - 1] : 0;
  curs[o0]     += run;
  curs[o0 + 1] += run + s0;
  curs[o0 + 2] += run + s0 + s1;
  curs[o0 + 3] += run + s0 + s1 + s2;
  if (b == 0) {
    off[o0] = run;
    off[o0 + 1] = run + s0;
    off[o0 + 2] = run + s0 + s1;
    off[o0 + 3] = run + s0 + s1 + s2;
    if (t == 255) off[KCAP] = wsum[255];
  }
  __syncthreads();
  int s = b * eps;
  int e = s + eps; if (e > n_edge) e = n_edge;
  for (int i = s + t; i < e; i += 256) {
    uint2 v = pa[i];
    if (v.x == 0xFFFFFFFFu) continue;
    int o = (v.x >> 20) & (KCAP - 1);
    int slot = atomicAdd(&curs[o], 1);
    sorted[slot] = v;
  }
}

// ============ per-obj LDS accumulation -> dense AB row ============
__global__ __launch_bounds__(256) void k_agg(const uint2* __restrict__ sorted,
                                             const int* __restrict__ off,
                                             float* __restrict__ AB) {
  __shared__ float coef[CW];
  int o = blockIdx.x;
  for (int i = threadIdx.x; i < CW; i += 256) coef[i] = 0.f;
  __syncthreads();
  int s = off[o], e = off[o + 1];
  for (int i = s + threadIdx.x; i < e; i += 256) {
    uint2 v = sorted[i];
    float a = __uint_as_float(v.y);
    atomicAdd(&coef[v.x & (KCAP - 1)], a);
    atomicAdd(&coef[KCAP + ((v.x >> 10) & (KCAP - 1))], a);
  }
  __syncthreads();
  float4* abr = (float4*)(AB + (size_t)o * CW);
  for (int i = threadIdx.x; i < CW / 4; i += 256) abr[i] = ((const float4*)coef)[i];
}

// ============ split-K GEMM (tail-zero lives in k_pre) ============
__global__ __launch_bounds__(512) void k_gemm2(const float* __restrict__ AB,
                                               const float* __restrict__ T,
                                               float* __restrict__ part) {
  __shared__ float sh[MT2][KCH2 + 4];
  int mt = blockIdx.x / NKC2;
  int kc = blockIdx.x % NKC2;
  int m0 = mt * MT2, k0 = kc * KCH2;
  for (int i = threadIdx.x; i < MT2 * (KCH2 / 4); i += 512) {
    int r = i >> 5, kq = i & 31;
    *(float4*)&sh[r][kq * 4] = *(const float4*)(AB + (long long)(m0 + r) * CW + k0 + kq * 4);
  }
  __syncthreads();
  int cg = threadIdx.x & 31;
  int rg = threadIdx.x >> 5;
  const float4* T4 = (const float4*)T;
  float4 acc0 = {0,0,0,0}, acc1 = {0,0,0,0}, acc2 = {0,0,0,0}, acc3 = {0,0,0,0};
#pragma unroll 4
  for (int k = 0; k < KCH2; ++k) {
    float4 tv = T4[(long long)(k0 + k) * (DIM / 4) + cg];
    float a0 = sh[rg * 4 + 0][k];
    float a1 = sh[rg * 4 + 1][k];
    float a2 = sh[rg * 4 + 2][k];
    float a3 = sh[rg * 4 + 3][k];
    acc0.x += a0 * tv.x; acc0.y += a0 * tv.y; acc0.z += a0 * tv.z; acc0.w += a0 * tv.w;
    acc1.x += a1 * tv.x; acc1.y += a1 * tv.y; acc1.z += a1 * tv.z; acc1.w += a1 * tv.w;
    acc2.x += a2 * tv.x; acc2.y += a2 * tv.y; acc2.z += a2 * tv.z; acc2.w += a2 * tv.w;
    acc3.x += a3 * tv.x; acc3.y += a3 * tv.y; acc3.z += a3 * tv.z; acc3.w += a3 * tv.w;
  }
  float4* p = (float4*)(part + ((long long)kc * KCAP + m0 + rg * 4) * DIM) + cg;
  p[0 * (DIM / 4)] = acc0;
  p[1 * (DIM / 4)] = acc1;
  p[2 * (DIM / 4)] = acc2;
  p[3 * (DIM / 4)] = acc3;
}

// ============ reduce partials (live rows only) -> out ============
__global__ void k_outfin(const float* __restrict__ part, float* __restrict__ out, int MR) {
  long long total = (long long)MR * 32;
  long long i = (long long)blockIdx.x * blockDim.x + threadIdx.x;
  long long stride = (long long)gridDim.x * blockDim.x;
  const float4* p4 = (const float4*)part;
  float4* o4 = (float4*)out;
  for (; i < total; i += stride) {
    long long r = i >> 5;
    int c4 = (int)(i & 31);
    float4 v = {0.f, 0.f, 0.f, 0.f};
#pragma unroll
    for (int kc = 0; kc < NKC2; ++kc) {
      float4 t = p4[((long long)kc * KCAP + r) * 32 + c4];
      v.x += t.x; v.y += t.y; v.z += t.z; v.w += t.w;
    }
    o4[i] = v;
  }
}

// ============ general fallback: one wave per listed edge, adds onto out ============
__global__ void k_fallback(const int* __restrict__ edges, const float* __restrict__ hidden,
                           const float* __restrict__ rela, const float* __restrict__ P2,
                           const float* __restrict__ C4, const float* __restrict__ Ws,
                           const float* __restrict__ w_alpha, const float* __restrict__ w_alpha_b,
                           const float* __restrict__ Wh, const int* __restrict__ left_ptr,
                           const int* __restrict__ fb_list, const int* __restrict__ fb_count,
                           float* __restrict__ out) {
  int nfb = fb_count[0];
  if (nfb == 0) return;
  int wave = (blockIdx.x * blockDim.x + threadIdx.x) >> 6;
  int nw = (gridDim.x * blockDim.x) >> 6;
  int lane = threadIdx.x & 63;
  int left = left_ptr[0];
  for (int i = wave; i < nfb; i += nw) {
    int e = fb_list[i];
    int head = edges[(long long)e * 6 + 1];
    int rel  = edges[(long long)e * 6 + 2];
    int tail = edges[(long long)e * 6 + 3];
    int sub  = edges[(long long)e * 6 + 4];
    int obj  = edges[(long long)e * 6 + 5];
    int c = ((head >= left) ? 2 : 0) | ((tail >= left) ? 1 : 0);
    float pre0 = P2[(long long)rel * DIM + lane] + C4[c * DIM + lane];
    float pre1 = P2[(long long)rel * DIM + 64 + lane] + C4[c * DIM + 64 + lane];
    for (int k = 0; k < DIM; ++k) {
      float h = hidden[(long long)sub * DIM + k];
      pre0 += h * Ws[k * DIM + lane];
      pre1 += h * Ws[k * DIM + 64 + lane];
    }
    float s = fmaxf(pre0, 0.f) * w_alpha[lane] + fmaxf(pre1, 0.f) * w_alpha[64 + lane];
    for (int d = 1; d < 64; d <<= 1) s += __shfl_xor(s, d);
    float alpha = 1.f / (1.f + expf(-(s + w_alpha_b[0])));
    float o0 = 0.f, o1 = 0.f;
    for (int k = 0; k < DIM; ++k) {
      float m = hidden[(long long)sub * DIM + k] + rela[(long long)rel * DIM + k];
      o0 += m * Wh[k * DIM + lane];
      o1 += m * Wh[k * DIM + 64 + lane];
    }
    atomicAdd(&out[(long long)obj * DIM + lane], alpha * o0);
    atomicAdd(&out[(long long)obj * DIM + 64 + lane], alpha * o1);
  }
}

extern "C" void kernel_launch(void* const* d_in, const int* in_sizes, int n_in,
                              void* d_out, int out_size, void* d_ws, size_t ws_size,
                              hipStream_t stream) {
  const float* hidden    = (const float*)d_in[0];
  const int*   edges     = (const int*)d_in[1];
  const float* kg_table  = (const float*)d_in[2];
  const float* rela      = (const float*)d_in[3];
  const float* Ws        = (const float*)d_in[4];
  const float* Wr        = (const float*)d_in[5];
  const float* Wkg_w     = (const float*)d_in[6];
  const float* Wkg_b     = (const float*)d_in[7];
  const float* w_alpha   = (const float*)d_in[8];
  const float* w_alpha_b = (const float*)d_in[9];
  const float* Wh        = (const float*)d_in[10];
  const int*   left_ptr  = (const int*)d_in[12];

  int n_node = out_size / DIM;
  int n_edge = in_sizes[1] / 6;
  int n_rel  = in_sizes[3] / DIM;
  int MR  = n_node < KCAP ? n_node : KCAP;
  int NR2 = n_rel < KCAP ? n_rel : KCAP;
  int eps = (n_edge + NB_SORT - 1) / NB_SORT;

  int nbA   = KCAP / 32;                               // 32
  int nbP2C = (NR2 + 31) / 32;
  int nbD   = (n_rel > NR2) ? (n_rel - NR2 + 31) / 32 : 0;
  int n_relpad = ((n_rel + 31) / 32) * 32;
  int NR2pad   = nbP2C * 32;

  char* ws = (char*)d_ws;
  size_t o = 0;
  auto alloc = [&](size_t b) { size_t r = o; o += (b + 255) & ~(size_t)255; return r; };
  float*    AB       = (float*)(ws + alloc((size_t)KCAP * CW * 4));           // 8 MB
  float*    T        = (float*)(ws + alloc((size_t)CW * DIM * 4));            // 1 MB
  _Float16* P1h      = (_Float16*)(ws + alloc((size_t)KCAP * DIM * 2));       // 256 KB
  float*    P2       = (float*)(ws + alloc((size_t)n_relpad * DIM * 4));
  _Float16* P2Ch     = (_Float16*)(ws + alloc((size_t)NR2pad * 4 * DIM * 2)); // 1 MB
  float*    C4       = (float*)(ws + alloc(4 * DIM * 4));
  float*    part     = (float*)(ws + alloc((size_t)NKC2 * KCAP * DIM * 4));   // 8 MB
  uint2*    pa       = (uint2*)(ws + alloc((size_t)n_edge * 8));              // 5 MB
  uint2*    sorted   = (uint2*)(ws + alloc((size_t)n_edge * 8));              // 5 MB
  int*      counts   = (int*)(ws + alloc((size_t)NB_SORT * KCAP * 4));        // 512 KB
  int*      off      = (int*)(ws + alloc((size_t)(KCAP + 1) * 4));
  int*      fb_list  = (int*)(ws + alloc((size_t)n_edge * 4));
  int*      fb_count = (int*)(ws + alloc(4));
  float*    out  = (float*)d_out;

  // fused precompute + histogram + out-tail-zero (one dispatch, multi-region)
  int nblocks = 3 * nbA + nbP2C + nbD + 1 + NB_SORT + NTZ;
  k_pre<<<nblocks, 256, 0, stream>>>(
      hidden, rela, kg_table, Ws, Wr, Wh, Wkg_w, Wkg_b, edges, n_edge, eps,
      P1h, P2, P2Ch, T, C4, counts, fb_count, out, n_node,
      MR, n_rel, NR2, nbA, nbP2C, nbD);

  // alpha + packed payload (fp16 packed math, 8 lanes/edge)
  int nb = (n_edge + EPB - 1) / EPB;
  k_alpha<<<nb, 256, 0, stream>>>(edges, n_edge, P1h, P2Ch, w_alpha, w_alpha_b,
                                  left_ptr, pa, fb_list, fb_count, MR, NR2);

  // counting-sort scatter (LDS cursors)
  k_scatter<<<NB_SORT, 256, 0, stream>>>(pa, n_edge, eps, counts, sorted, off);

  // per-obj LDS accumulation -> dense AB rows
  k_agg<<<KCAP, 256, 0, stream>>>(sorted, off, AB);

  // split-K GEMM into partials, then reduce live rows
  k_gemm2<<<NGEMM, 512, 0, stream>>>(AB, T, part);
  k_outfin<<<256, 256, 0, stream>>>(part, out, MR);

  // general-index fallback (empty for this dataset)
  k_fallback<<<64, 256, 0, stream>>>(edges, hidden, rela, P2, C4, Ws, w_alpha,
                                     w_alpha_b, Wh, left_ptr, fb_list, fb_count, out);
}